// Round 1
// baseline (32.969 us; speedup 1.0000x reference)
//
#include <hip/hip_runtime.h>

#define DDIM 128

__global__ __launch_bounds__(128) void transr_kernel(
    const int* __restrict__ h, const int* __restrict__ r,
    const int* __restrict__ pos_t, const int* __restrict__ neg_t,
    const float* __restrict__ ent, const float* __restrict__ rel,
    const float* __restrict__ M, float* __restrict__ out, int B)
{
    const int b = blockIdx.x;
    const int t = threadIdx.x;

    __shared__ float sh[3][DDIM];

    // wave-uniform index loads (compiler emits s_load)
    const int hb = h[b];
    const int rb = r[b];
    const int pb = pos_t[b];
    const int nb = neg_t[b];

    // stage gathered embeddings into LDS (coalesced 512B per vector)
    sh[0][t] = ent[(size_t)hb * DDIM + t];
    sh[1][t] = ent[(size_t)pb * DDIM + t];
    sh[2][t] = ent[(size_t)nb * DDIM + t];

    // r_e output (output slot 1): pure gather copy
    out[(size_t)B * DDIM + (size_t)b * DDIM + t] = rel[(size_t)rb * DDIM + t];

    __syncthreads();

    const float* __restrict__ W = M + (size_t)rb * DDIM * DDIM;

    float ah = 0.f, ap = 0.f, an = 0.f;

    #pragma unroll 4
    for (int d = 0; d < DDIM; d += 4) {
        // broadcast reads from LDS as float4 (one ds_read_b128 per wave per vec)
        const float4 xh = *(const float4*)&sh[0][d];
        const float4 xp = *(const float4*)&sh[1][d];
        const float4 xn = *(const float4*)&sh[2][d];
        // coalesced W column reads: wave's 64 lanes hit 256B contiguous
        const float w0 = W[(size_t)(d + 0) * DDIM + t];
        const float w1 = W[(size_t)(d + 1) * DDIM + t];
        const float w2 = W[(size_t)(d + 2) * DDIM + t];
        const float w3 = W[(size_t)(d + 3) * DDIM + t];

        ah = fmaf(xh.x, w0, ah); ap = fmaf(xp.x, w0, ap); an = fmaf(xn.x, w0, an);
        ah = fmaf(xh.y, w1, ah); ap = fmaf(xp.y, w1, ap); an = fmaf(xn.y, w1, an);
        ah = fmaf(xh.z, w2, ah); ap = fmaf(xp.z, w2, ap); an = fmaf(xn.z, w2, an);
        ah = fmaf(xh.w, w3, ah); ap = fmaf(xp.w, w3, ap); an = fmaf(xn.w, w3, an);
    }

    // outputs: [trans_h | r_e | trans_pos | trans_neg], each B*D, row-major
    out[(size_t)b * DDIM + t]                       = ah;
    out[2 * (size_t)B * DDIM + (size_t)b * DDIM + t] = ap;
    out[3 * (size_t)B * DDIM + (size_t)b * DDIM + t] = an;
}

extern "C" void kernel_launch(void* const* d_in, const int* in_sizes, int n_in,
                              void* d_out, int out_size, void* d_ws, size_t ws_size,
                              hipStream_t stream) {
    const int*   h     = (const int*)d_in[0];
    const int*   r     = (const int*)d_in[1];
    const int*   pos_t = (const int*)d_in[2];
    const int*   neg_t = (const int*)d_in[3];
    const float* ent   = (const float*)d_in[4];
    const float* rel   = (const float*)d_in[5];
    const float* M     = (const float*)d_in[6];
    float*       out   = (float*)d_out;

    const int B = in_sizes[0];

    transr_kernel<<<dim3(B), dim3(DDIM), 0, stream>>>(
        h, r, pos_t, neg_t, ent, rel, M, out, B);
}